// Round 1
// baseline (453.976 us; speedup 1.0000x reference)
//
#include <hip/hip_runtime.h>
#include <math.h>

#define B_ 64
#define E_ 512
#define N_ 2048
#define EPSF 1e-8f

// ws layout (float slots)
#define OFF_ROWMEAN 0            // B*E = 32768
#define OFF_ROWINV  32768        // B*E = 32768
#define OFF_COLSUM  65536        // B*N = 131072
#define OFF_MM      196608       // 8 u32 (6 used: min[3], max[3])
#define OFF_RAW     196616       // B*3*4096 = 786432
#define OFF_ZPART   983048       // 16*B*4096 = 4194304
// total = 5,177,352 floats ~= 19.8 MB

// order-preserving float<->uint map for atomic min/max
__device__ __forceinline__ unsigned mapf(float x) {
    unsigned u = __float_as_uint(x);
    return (u & 0x80000000u) ? ~u : (u | 0x80000000u);
}
__device__ __forceinline__ float unmapf(unsigned m) {
    unsigned u = (m & 0x80000000u) ? (m ^ 0x80000000u) : ~m;
    return __uint_as_float(u);
}

// ---------- kernel 1: per-row sum/sumsq -> mean, 1/(norm+eps) ----------
// grid (E/4, B), block 256: one wave per row
__global__ __launch_bounds__(256) void k_rowstats(const float* __restrict__ x,
                                                  float* __restrict__ rowmean,
                                                  float* __restrict__ rowinv) {
    int b = blockIdx.y;
    int e = blockIdx.x * 4 + (threadIdx.x >> 6);
    int lane = threadIdx.x & 63;
    const float4* row = (const float4*)(x + ((size_t)b * E_ + e) * N_);
    float s = 0.f, sq = 0.f;
#pragma unroll
    for (int i = 0; i < 8; ++i) {
        float4 v = row[lane + 64 * i];
        s  += v.x + v.y + v.z + v.w;
        sq += v.x * v.x + v.y * v.y + v.z * v.z + v.w * v.w;
    }
#pragma unroll
    for (int m = 32; m; m >>= 1) {
        s  += __shfl_xor(s, m, 64);
        sq += __shfl_xor(sq, m, 64);
    }
    if (lane == 0) {
        float mean = s * (1.0f / N_);
        float var = sq - s * s * (1.0f / N_);
        if (var < 0.f) var = 0.f;
        rowmean[b * E_ + e] = mean;
        rowinv[b * E_ + e] = 1.0f / (sqrtf(var) + EPSF);
    }
}

// ---------- kernel 2: column sums (for spatial view) ----------
// grid (32, B): x = nchunk(8) + 8*echunk(4); block 256, one column per thread
__global__ __launch_bounds__(256) void k_colsum(const float* __restrict__ x,
                                                float* __restrict__ colsum) {
    int b = blockIdx.y;
    int nc = blockIdx.x & 7;
    int ec = blockIdx.x >> 3;
    int n = nc * 256 + threadIdx.x;
    const float* p = x + ((size_t)b * E_ + ec * 128) * N_ + n;
    float s = 0.f;
#pragma unroll 8
    for (int e = 0; e < 128; ++e) s += p[(size_t)e * N_];
    atomicAdd(&colsum[b * N_ + n], s);
}

// ---------- kernel 3: Z = Y Y^T partials, Y built on the fly ----------
// Y[o] = 0.5*((x[8o+3]-m0)*s0 + (x[8o+4]-m1)*s1); K split into 16 chunks of 128
// grid (B, 16), block 256; LDS tile 64 x 128 (stride 129 -> <=2-way banks)
__global__ __launch_bounds__(256) void k_z(const float* __restrict__ x,
                                           const float* __restrict__ rowmean,
                                           const float* __restrict__ rowinv,
                                           float* __restrict__ zpart) {
    __shared__ float yt[64 * 129];
    int b = blockIdx.x;
    int s = blockIdx.y;
    int k0 = s * 128;
    int t = threadIdx.x;

    int kk = t & 127;
    int oh = t >> 7;           // 0 or 1: two rows of Y per iteration
    for (int oo = 0; oo < 64; oo += 2) {
        int o = oo + oh;
        int r0 = 8 * o + 3, r1 = 8 * o + 4;
        float m0 = rowmean[b * E_ + r0], i0 = rowinv[b * E_ + r0];
        float m1 = rowmean[b * E_ + r1], i1 = rowinv[b * E_ + r1];
        float a = x[((size_t)b * E_ + r0) * N_ + k0 + kk];
        float c = x[((size_t)b * E_ + r1) * N_ + k0 + kk];
        yt[o * 129 + kk] = 0.5f * ((a - m0) * i0 + (c - m1) * i1);
    }
    __syncthreads();

    int ti = t >> 4, tj = t & 15;   // 4x4 output tile per thread
    float acc[4][4] = {};
#pragma unroll 4
    for (int k = 0; k < 128; ++k) {
        float ai[4], aj[4];
#pragma unroll
        for (int a = 0; a < 4; ++a) ai[a] = yt[(4 * ti + a) * 129 + k];
#pragma unroll
        for (int c = 0; c < 4; ++c) aj[c] = yt[(4 * tj + c) * 129 + k];
#pragma unroll
        for (int a = 0; a < 4; ++a)
#pragma unroll
            for (int c = 0; c < 4; ++c) acc[a][c] += ai[a] * aj[c];
    }
    float* zp = zpart + ((size_t)s * B_ + b) * 4096;
#pragma unroll
    for (int a = 0; a < 4; ++a)
#pragma unroll
        for (int c = 0; c < 4; ++c)
            zp[(4 * ti + a) * 64 + (4 * tj + c)] = acc[a][c];
}

// ---------- kernel 4: build raw 64x64 views + global min/max ----------
// grid (B, 3), block 256
__global__ __launch_bounds__(256) void k_views(const float* __restrict__ rowmean,
                                               const float* __restrict__ colsum,
                                               const float* __restrict__ zpart,
                                               float* __restrict__ raw,
                                               unsigned* __restrict__ mm) {
    int b = blockIdx.x, v = blockIdx.y;
    int t = threadIdx.x;
    __shared__ float g[2116];
    __shared__ int   ti0[64];
    __shared__ int   ti1[64];
    __shared__ float tw[64];
    __shared__ float smin[4], smax[4];

    int gs = (v == 0) ? 23 : 46;
    if (v < 2) {
        int L = (v == 0) ? 512 : 2048;
        int gg = gs * gs;
        const float* src = (v == 0) ? (rowmean + b * E_) : (colsum + b * N_);
        float sc = (v == 0) ? 1.0f : (1.0f / 512.0f);
        for (int i = t; i < gg; i += 256) g[i] = (i < L) ? src[i] * sc : 0.f;
        if (t < 64) {
            // replicate np: src=(o+0.5)*(gs/64)-0.5, clip, floor, w after clip
            double scd = (double)gs / 64.0;
            double sp = ((double)t + 0.5) * scd - 0.5;
            if (sp < 0.0) sp = 0.0;
            double up = (double)(gs - 1);
            if (sp > up) sp = up;
            int i0 = (int)sp;              // sp >= 0 so trunc == floor
            ti0[t] = i0;
            ti1[t] = (i0 + 1 < gs) ? i0 + 1 : gs - 1;
            tw[t] = (float)(sp - (double)i0);
        }
    }
    __syncthreads();

    float lmin = INFINITY, lmax = -INFINITY;
    for (int it = 0; it < 16; ++it) {
        int pix = t + 256 * it;
        float val;
        if (v == 2) {
            val = 0.f;
#pragma unroll
            for (int s = 0; s < 16; ++s)
                val += zpart[((size_t)s * B_ + b) * 4096 + pix];
        } else {
            int o = pix >> 6, p = pix & 63;
            int i0 = ti0[o], i1 = ti1[o];
            float wh = tw[o];
            int j0 = ti0[p], j1 = ti1[p];
            float ww = tw[p];
            float top = g[i0 * gs + j0] * (1.f - ww) + g[i0 * gs + j1] * ww;
            float bot = g[i1 * gs + j0] * (1.f - ww) + g[i1 * gs + j1] * ww;
            val = top * (1.f - wh) + bot * wh;
        }
        raw[((size_t)b * 3 + v) * 4096 + pix] = val;
        lmin = fminf(lmin, val);
        lmax = fmaxf(lmax, val);
    }

    int lane = t & 63, wid = t >> 6;
#pragma unroll
    for (int m = 32; m; m >>= 1) {
        lmin = fminf(lmin, __shfl_xor(lmin, m, 64));
        lmax = fmaxf(lmax, __shfl_xor(lmax, m, 64));
    }
    if (lane == 0) { smin[wid] = lmin; smax[wid] = lmax; }
    __syncthreads();
    if (t == 0) {
        float mn = fminf(fminf(smin[0], smin[1]), fminf(smin[2], smin[3]));
        float mx = fmaxf(fmaxf(smax[0], smax[1]), fmaxf(smax[2], smax[3]));
        atomicMin(&mm[v], mapf(mn));
        atomicMax(&mm[3 + v], mapf(mx));
    }
}

// ---------- kernel 5: global minmax-normalize -> out ----------
// grid (B, 3), block 256
__global__ __launch_bounds__(256) void k_norm(const float* __restrict__ raw,
                                              const unsigned* __restrict__ mm,
                                              float* __restrict__ out) {
    int b = blockIdx.x, v = blockIdx.y;
    int t = threadIdx.x;
    float lo = unmapf(mm[v]);
    float hi = unmapf(mm[3 + v]);
    float d = hi - lo;
    bool zero = (d < EPSF);
    float inv = 1.0f / (d + EPSF);
    size_t base = ((size_t)b * 3 + v) * 4096;
    for (int it = 0; it < 16; ++it) {
        int pix = t + 256 * it;
        float r = raw[base + pix];
        out[base + pix] = zero ? 0.f : (r - lo) * inv;
    }
}

extern "C" void kernel_launch(void* const* d_in, const int* in_sizes, int n_in,
                              void* d_out, int out_size, void* d_ws, size_t ws_size,
                              hipStream_t stream) {
    const float* x = (const float*)d_in[0];
    float* ws = (float*)d_ws;
    float* rowmean = ws + OFF_ROWMEAN;
    float* rowinv  = ws + OFF_ROWINV;
    float* colsum  = ws + OFF_COLSUM;
    unsigned* mm   = (unsigned*)(ws + OFF_MM);
    float* raw     = ws + OFF_RAW;
    float* zpart   = ws + OFF_ZPART;
    float* out     = (float*)d_out;

    // ws is poisoned 0xAA before every timed call: re-init accumulators/trackers
    hipMemsetAsync(colsum, 0, (size_t)B_ * N_ * sizeof(float), stream);
    hipMemsetAsync(mm, 0xFF, 3 * sizeof(unsigned), stream);       // min trackers
    hipMemsetAsync(mm + 3, 0x00, 3 * sizeof(unsigned), stream);   // max trackers

    k_rowstats<<<dim3(E_ / 4, B_), 256, 0, stream>>>(x, rowmean, rowinv);
    k_colsum<<<dim3(32, B_), 256, 0, stream>>>(x, colsum);
    k_z<<<dim3(B_, 16), 256, 0, stream>>>(x, rowmean, rowinv, zpart);
    k_views<<<dim3(B_, 3), 256, 0, stream>>>(rowmean, colsum, zpart, raw, mm);
    k_norm<<<dim3(B_, 3), 256, 0, stream>>>(raw, mm, out);
}

// Round 2
// 416.602 us; speedup vs baseline: 1.0897x; 1.0897x over previous
//
#include <hip/hip_runtime.h>
#include <math.h>

#define B_ 64
#define E_ 512
#define N_ 2048
#define EPSF 1e-8f

// ws layout (float slots)
#define OFF_ROWMEAN 0              // B*E = 32768
#define OFF_ROWINV  32768          // B*E = 32768
#define OFF_COLPART 65536          // 16*B*N = 2097152 (per-echunk colsum partials)
#define OFF_MM      2162688        // 8 u32 (min[3], max[3])
#define OFF_RAW     2162696        // B*3*4096 = 786432
#define OFF_ZPART   2949128        // 16*B*4096 = 4194304
// total ~7.14M floats ~28.6 MB

// order-preserving float<->uint map for atomic min/max
__device__ __forceinline__ unsigned mapf(float x) {
    unsigned u = __float_as_uint(x);
    return (u & 0x80000000u) ? ~u : (u | 0x80000000u);
}
__device__ __forceinline__ float unmapf(unsigned m) {
    unsigned u = (m & 0x80000000u) ? (m ^ 0x80000000u) : ~m;
    return __uint_as_float(u);
}

// ---------- kernel 1: fused row stats + column-sum partials (ONE 268MB pass) ----------
// grid (16, B), block 256 = 4 waves; wave w handles rows [ec*32 + w*8, +8).
// Lane's float4 columns are row-invariant -> 32 col accumulators in VGPRs.
__global__ __launch_bounds__(256) void k_stats(const float* __restrict__ x,
                                               float* __restrict__ rowmean,
                                               float* __restrict__ rowinv,
                                               float* __restrict__ colpart) {
    __shared__ __align__(16) float cs[4][N_];   // 32 KB
    int b = blockIdx.y, ec = blockIdx.x;
    int t = threadIdx.x, w = t >> 6, lane = t & 63;
    float colacc[32];
#pragma unroll
    for (int i = 0; i < 32; ++i) colacc[i] = 0.f;
    int ebase = ec * 32 + w * 8;
#pragma unroll 1
    for (int r = 0; r < 8; ++r) {
        int e = ebase + r;
        const float4* row = (const float4*)(x + ((size_t)b * E_ + e) * N_);
        float s = 0.f, sq = 0.f;
#pragma unroll
        for (int i = 0; i < 8; ++i) {
            float4 v = row[lane + 64 * i];
            s += v.x + v.y + v.z + v.w;
            sq = fmaf(v.x, v.x, sq);
            sq = fmaf(v.y, v.y, sq);
            sq = fmaf(v.z, v.z, sq);
            sq = fmaf(v.w, v.w, sq);
            colacc[4 * i + 0] += v.x;
            colacc[4 * i + 1] += v.y;
            colacc[4 * i + 2] += v.z;
            colacc[4 * i + 3] += v.w;
        }
#pragma unroll
        for (int m = 32; m; m >>= 1) {
            s += __shfl_xor(s, m, 64);
            sq += __shfl_xor(sq, m, 64);
        }
        if (lane == 0) {
            float mean = s * (1.0f / N_);
            float var = sq - s * s * (1.0f / N_);
            if (var < 0.f) var = 0.f;
            rowmean[b * E_ + e] = mean;
            rowinv[b * E_ + e] = 1.0f / (sqrtf(var) + EPSF);
        }
    }
    // wave w dumps its 2048 col partials (lane covers cols 4*lane+256*i+{0..3})
    float4* slice = (float4*)cs[w];
#pragma unroll
    for (int i = 0; i < 8; ++i)
        slice[lane + 64 * i] = make_float4(colacc[4 * i], colacc[4 * i + 1],
                                           colacc[4 * i + 2], colacc[4 * i + 3]);
    __syncthreads();
    float* cp = colpart + ((size_t)ec * B_ + b) * N_;
    for (int c = t; c < N_; c += 256)
        cp[c] = cs[0][c] + cs[1][c] + cs[2][c] + cs[3][c];
}

// ---------- kernel 2: Z = Y Y^T, one wave per (b, kchunk), 8x8 reg tile ----------
// Y[o] = 0.5*((x[8o+3]-m0)*i0 + (x[8o+4]-m1)*i1), K split 16 x 128.
// LDS layout swizzled: word(o, k=4m+j) = o*128 + 4*(m ^ (o>>3)) + j
//  -> b128 reads over rows 8ti+a hit banks 4*((m^ti)&7): conflict-free.
__global__ __launch_bounds__(64) void k_z(const float* __restrict__ x,
                                          const float* __restrict__ rowmean,
                                          const float* __restrict__ rowinv,
                                          float* __restrict__ zpart) {
    __shared__ __align__(16) float Y[64 * 128];   // 32 KB, one wave per block
    int b = blockIdx.x;
    int kc = blockIdx.y;
    int k0 = kc * 128;
    int lane = threadIdx.x;
    const float* xb = x + (size_t)b * E_ * N_;
    const float* rm = rowmean + b * E_;
    const float* ri = rowinv + b * E_;
    int mg = lane >> 1;              // 4-float group index 0..31
    int jj = (lane & 1) * 2;         // position within group
#pragma unroll 4
    for (int o = 0; o < 64; ++o) {
        int r0 = 8 * o + 3, r1 = 8 * o + 4;
        float2 a = *(const float2*)(xb + (size_t)r0 * N_ + k0 + 2 * lane);
        float2 c = *(const float2*)(xb + (size_t)r1 * N_ + k0 + 2 * lane);
        float m0 = rm[r0], s0 = ri[r0];
        float m1 = rm[r1], s1 = ri[r1];
        float2 yv;
        yv.x = 0.5f * ((a.x - m0) * s0 + (c.x - m1) * s1);
        yv.y = 0.5f * ((a.y - m0) * s0 + (c.y - m1) * s1);
        *(float2*)&Y[o * 128 + 4 * (mg ^ (o >> 3)) + jj] = yv;
    }
    __syncthreads();   // single wave: cheap; orders LDS writes->reads

    int ti = lane >> 3, tj = lane & 7;
    float acc[8][8];
#pragma unroll
    for (int i = 0; i < 8; ++i)
#pragma unroll
        for (int j = 0; j < 8; ++j) acc[i][j] = 0.f;

#pragma unroll 2
    for (int m4 = 0; m4 < 32; ++m4) {
        float4 av[8], bv[8];
#pragma unroll
        for (int a = 0; a < 8; ++a)
            av[a] = *(const float4*)&Y[(8 * ti + a) * 128 + 4 * (m4 ^ ti)];
#pragma unroll
        for (int c = 0; c < 8; ++c)
            bv[c] = *(const float4*)&Y[(8 * tj + c) * 128 + 4 * (m4 ^ tj)];
#pragma unroll
        for (int a = 0; a < 8; ++a)
#pragma unroll
            for (int c = 0; c < 8; ++c) {
                acc[a][c] = fmaf(av[a].x, bv[c].x, acc[a][c]);
                acc[a][c] = fmaf(av[a].y, bv[c].y, acc[a][c]);
                acc[a][c] = fmaf(av[a].z, bv[c].z, acc[a][c]);
                acc[a][c] = fmaf(av[a].w, bv[c].w, acc[a][c]);
            }
    }
    float* zp = zpart + ((size_t)kc * B_ + b) * 4096;
#pragma unroll
    for (int a = 0; a < 8; ++a) {
        int rr = (8 * ti + a) * 64 + 8 * tj;
        *(float4*)&zp[rr]     = make_float4(acc[a][0], acc[a][1], acc[a][2], acc[a][3]);
        *(float4*)&zp[rr + 4] = make_float4(acc[a][4], acc[a][5], acc[a][6], acc[a][7]);
    }
}

// ---------- kernel 3: build raw 64x64 views + global min/max ----------
// grid (B, 3), block 256
__global__ __launch_bounds__(256) void k_views(const float* __restrict__ rowmean,
                                               const float* __restrict__ colpart,
                                               const float* __restrict__ zpart,
                                               float* __restrict__ raw,
                                               unsigned* __restrict__ mm) {
    int b = blockIdx.x, v = blockIdx.y;
    int t = threadIdx.x;
    __shared__ float g[2116];
    __shared__ int   ti0[64];
    __shared__ int   ti1[64];
    __shared__ float tw[64];
    __shared__ float smin[4], smax[4];

    int gs = (v == 0) ? 23 : 46;
    if (v < 2) {
        int L = (v == 0) ? 512 : 2048;
        int gg = gs * gs;
        for (int i = t; i < gg; i += 256) {
            float val = 0.f;
            if (i < L) {
                if (v == 0) {
                    val = rowmean[b * E_ + i];
                } else {
#pragma unroll
                    for (int ch = 0; ch < 16; ++ch)
                        val += colpart[((size_t)ch * B_ + b) * N_ + i];
                    val *= (1.0f / 512.0f);
                }
            }
            g[i] = val;
        }
        if (t < 64) {
            // replicate np: src=(o+0.5)*(gs/64)-0.5, clip, floor, w after clip
            double scd = (double)gs / 64.0;
            double sp = ((double)t + 0.5) * scd - 0.5;
            if (sp < 0.0) sp = 0.0;
            double up = (double)(gs - 1);
            if (sp > up) sp = up;
            int i0 = (int)sp;
            ti0[t] = i0;
            ti1[t] = (i0 + 1 < gs) ? i0 + 1 : gs - 1;
            tw[t] = (float)(sp - (double)i0);
        }
    }
    __syncthreads();

    float lmin = INFINITY, lmax = -INFINITY;
    for (int it = 0; it < 16; ++it) {
        int pix = t + 256 * it;
        float val;
        if (v == 2) {
            val = 0.f;
#pragma unroll
            for (int s = 0; s < 16; ++s)
                val += zpart[((size_t)s * B_ + b) * 4096 + pix];
        } else {
            int o = pix >> 6, p = pix & 63;
            int i0 = ti0[o], i1 = ti1[o];
            float wh = tw[o];
            int j0 = ti0[p], j1 = ti1[p];
            float ww = tw[p];
            float top = g[i0 * gs + j0] * (1.f - ww) + g[i0 * gs + j1] * ww;
            float bot = g[i1 * gs + j0] * (1.f - ww) + g[i1 * gs + j1] * ww;
            val = top * (1.f - wh) + bot * wh;
        }
        raw[((size_t)b * 3 + v) * 4096 + pix] = val;
        lmin = fminf(lmin, val);
        lmax = fmaxf(lmax, val);
    }

    int lane = t & 63, wid = t >> 6;
#pragma unroll
    for (int m = 32; m; m >>= 1) {
        lmin = fminf(lmin, __shfl_xor(lmin, m, 64));
        lmax = fmaxf(lmax, __shfl_xor(lmax, m, 64));
    }
    if (lane == 0) { smin[wid] = lmin; smax[wid] = lmax; }
    __syncthreads();
    if (t == 0) {
        float mn = fminf(fminf(smin[0], smin[1]), fminf(smin[2], smin[3]));
        float mx = fmaxf(fmaxf(smax[0], smax[1]), fmaxf(smax[2], smax[3]));
        atomicMin(&mm[v], mapf(mn));
        atomicMax(&mm[3 + v], mapf(mx));
    }
}

// ---------- kernel 4: global minmax-normalize -> out ----------
__global__ __launch_bounds__(256) void k_norm(const float* __restrict__ raw,
                                              const unsigned* __restrict__ mm,
                                              float* __restrict__ out) {
    int b = blockIdx.x, v = blockIdx.y;
    int t = threadIdx.x;
    float lo = unmapf(mm[v]);
    float hi = unmapf(mm[3 + v]);
    float d = hi - lo;
    bool zero = (d < EPSF);
    float inv = 1.0f / (d + EPSF);
    size_t base = ((size_t)b * 3 + v) * 4096;
    for (int it = 0; it < 16; ++it) {
        int pix = t + 256 * it;
        float r = raw[base + pix];
        out[base + pix] = zero ? 0.f : (r - lo) * inv;
    }
}

extern "C" void kernel_launch(void* const* d_in, const int* in_sizes, int n_in,
                              void* d_out, int out_size, void* d_ws, size_t ws_size,
                              hipStream_t stream) {
    const float* x = (const float*)d_in[0];
    float* ws = (float*)d_ws;
    float* rowmean = ws + OFF_ROWMEAN;
    float* rowinv  = ws + OFF_ROWINV;
    float* colpart = ws + OFF_COLPART;
    unsigned* mm   = (unsigned*)(ws + OFF_MM);
    float* raw     = ws + OFF_RAW;
    float* zpart   = ws + OFF_ZPART;
    float* out     = (float*)d_out;

    // ws poisoned 0xAA before every timed call: re-init min/max trackers only
    hipMemsetAsync(mm, 0xFF, 3 * sizeof(unsigned), stream);       // min trackers
    hipMemsetAsync(mm + 3, 0x00, 3 * sizeof(unsigned), stream);   // max trackers

    k_stats<<<dim3(16, B_), 256, 0, stream>>>(x, rowmean, rowinv, colpart);
    k_z<<<dim3(B_, 16), 64, 0, stream>>>(x, rowmean, rowinv, zpart);
    k_views<<<dim3(B_, 3), 256, 0, stream>>>(rowmean, colpart, zpart, raw, mm);
    k_norm<<<dim3(B_, 3), 256, 0, stream>>>(raw, mm, out);
}